// Round 1
// baseline (713.867 us; speedup 1.0000x reference)
//
#include <hip/hip_runtime.h>

#define N_NODES 100000
#define N_EDGES 1600000
#define D_IN 64
#define D_OUT 64
#define E_DIM 32
#define KCAT 288          // 3*64 (S buckets) + 3*32 (T buckets)

// ---------------------------------------------------------------------------
// K0: zero the bucket region (own kernel: no hipMemsetAsync, capture-safe)
// ---------------------------------------------------------------------------
__global__ __launch_bounds__(256) void zero_buf(float4* __restrict__ p, long n4) {
    long i = (long)blockIdx.x * 256 + threadIdx.x;
    long stride = (long)gridDim.x * 256;
    float4 z = make_float4(0.f, 0.f, 0.f, 0.f);
    for (; i < n4; i += stride) p[i] = z;
}

// ---------------------------------------------------------------------------
// K1: x_out[n] = node_feature[n] @ W_node[node_type[n]]   (wave per node)
// ---------------------------------------------------------------------------
__global__ __launch_bounds__(256) void node_xform(const float* __restrict__ nf,
                                                  const float* __restrict__ Wn,
                                                  const int* __restrict__ ntype,
                                                  float* __restrict__ xout) {
    __shared__ float wl[2 * 64 * 64];   // 32 KB, both node-type matrices
    for (int i = threadIdx.x; i < 2 * 64 * 64; i += 256) wl[i] = Wn[i];
    __syncthreads();
    int wid = threadIdx.x >> 6, lane = threadIdx.x & 63;
    int n = blockIdx.x * 4 + wid;
    if (n >= N_NODES) return;
    int t = ntype[n];                       // wave-uniform
    float x = nf[n * 64 + lane];            // lane k holds row element k
    const float* wcol = &wl[t * 4096 + lane];  // column `lane`, stride 64 (2-way bank: free)
    float acc = 0.f;
#pragma unroll
    for (int k = 0; k < 64; ++k)
        acc = fmaf(__shfl(x, k), wcol[k * 64], acc);
    xout[n * 64 + lane] = acc;
}

// ---------------------------------------------------------------------------
// K2: scatter edges into buckets B[n][288]:
//     cols [t*64, t*64+64)      += x_out[src]      (edge type t)
//     cols [192+t*32, +32)      += edge_feature[e]
// ---------------------------------------------------------------------------
__global__ __launch_bounds__(256) void edge_scatter(const float* __restrict__ xout,
                                                    const float* __restrict__ ef,
                                                    const int* __restrict__ etype,
                                                    const int* __restrict__ eidx,
                                                    float* __restrict__ B) {
    int gwid = (int)((blockIdx.x * blockDim.x + threadIdx.x) >> 6);
    int lane = threadIdx.x & 63;
    int nwaves = (int)((gridDim.x * blockDim.x) >> 6);
    for (int e = gwid; e < N_EDGES; e += nwaves) {
        int t = etype[e];
        int s = eidx[e];             // edge_index[0][e]
        int d = eidx[N_EDGES + e];   // edge_index[1][e]
        float v = xout[(long)s * 64 + lane];
        atomicAdd(&B[(long)d * KCAT + t * 64 + lane], v);
        if (lane < 32) {
            float ev = ef[(long)e * 32 + lane];
            atomicAdd(&B[(long)d * KCAT + 192 + t * 32 + lane], ev);
        }
    }
}

// ---------------------------------------------------------------------------
// K3: out = B @ Wcat, Wcat[288][64] assembled on the fly from W_msg:
//     row r<192:  t=r>>6, kin=r&63 ; row r>=192: t=(r-192)>>5, kin=64+((r-192)&31)
// Tiled fp32 GEMM: 64 nodes x 64 cols per block, K-slice 32.
// ---------------------------------------------------------------------------
__global__ __launch_bounds__(256) void final_gemm(const float* __restrict__ B,
                                                  const float* __restrict__ Wm,
                                                  float* __restrict__ out) {
    __shared__ float As[64][33];   // +1 pad
    __shared__ float Ws[32][64];
    int tid = threadIdx.x;
    int n0 = blockIdx.x * 64;
    int tx = tid & 15;    // output col quad  (j = tx*4 .. +3)
    int ty = tid >> 4;    // node quad        (n = n0 + ty*4 .. +3)
    float acc[4][4] = {};

    for (int k0 = 0; k0 < KCAT; k0 += 32) {
        // stage A tile [64 nodes][32 k]
#pragma unroll
        for (int i = 0; i < 8; ++i) {
            int f = i * 256 + tid;
            int r = f >> 5, c = f & 31;
            int n = n0 + r;
            As[r][c] = (n < N_NODES) ? B[(long)n * KCAT + k0 + c] : 0.f;
        }
        // stage W tile [32 k][64 j] with Wcat remap
#pragma unroll
        for (int i = 0; i < 8; ++i) {
            int f = i * 256 + tid;
            int kk = f >> 6, j = f & 63;
            int r = k0 + kk;
            int t, kin;
            if (r < 192) { t = r >> 6; kin = r & 63; }
            else         { int q = r - 192; t = q >> 5; kin = 64 + (q & 31); }
            Ws[kk][j] = Wm[(t * 96 + kin) * 64 + j];
        }
        __syncthreads();
#pragma unroll
        for (int kk = 0; kk < 32; ++kk) {
            float a0 = As[ty * 4 + 0][kk];
            float a1 = As[ty * 4 + 1][kk];
            float a2 = As[ty * 4 + 2][kk];
            float a3 = As[ty * 4 + 3][kk];
            float4 w = *(const float4*)&Ws[kk][tx * 4];
            acc[0][0] = fmaf(a0, w.x, acc[0][0]); acc[0][1] = fmaf(a0, w.y, acc[0][1]);
            acc[0][2] = fmaf(a0, w.z, acc[0][2]); acc[0][3] = fmaf(a0, w.w, acc[0][3]);
            acc[1][0] = fmaf(a1, w.x, acc[1][0]); acc[1][1] = fmaf(a1, w.y, acc[1][1]);
            acc[1][2] = fmaf(a1, w.z, acc[1][2]); acc[1][3] = fmaf(a1, w.w, acc[1][3]);
            acc[2][0] = fmaf(a2, w.x, acc[2][0]); acc[2][1] = fmaf(a2, w.y, acc[2][1]);
            acc[2][2] = fmaf(a2, w.z, acc[2][2]); acc[2][3] = fmaf(a2, w.w, acc[2][3]);
            acc[3][0] = fmaf(a3, w.x, acc[3][0]); acc[3][1] = fmaf(a3, w.y, acc[3][1]);
            acc[3][2] = fmaf(a3, w.z, acc[3][2]); acc[3][3] = fmaf(a3, w.w, acc[3][3]);
        }
        __syncthreads();
    }
#pragma unroll
    for (int r = 0; r < 4; ++r) {
        int n = n0 + ty * 4 + r;
        if (n < N_NODES) {
            float4 v = make_float4(acc[r][0], acc[r][1], acc[r][2], acc[r][3]);
            *(float4*)&out[(long)n * 64 + tx * 4] = v;
        }
    }
}

// ---------------------------------------------------------------------------
// Fallback (ws too small): direct wave-per-edge, recompute x_src on the fly.
// Slow but correct and ws-free.
// ---------------------------------------------------------------------------
__global__ __launch_bounds__(256) void fallback_edge(const float* __restrict__ nf,
                                                     const float* __restrict__ ef,
                                                     const float* __restrict__ Wn,
                                                     const float* __restrict__ Wm,
                                                     const int* __restrict__ ntype,
                                                     const int* __restrict__ etype,
                                                     const int* __restrict__ eidx,
                                                     float* __restrict__ out) {
    __shared__ float wn[2 * 64 * 64];   // 32 KB
    __shared__ float wm[3 * 96 * 64];   // 72 KB
    for (int i = threadIdx.x; i < 2 * 64 * 64; i += 256) wn[i] = Wn[i];
    for (int i = threadIdx.x; i < 3 * 96 * 64; i += 256) wm[i] = Wm[i];
    __syncthreads();
    int wid = threadIdx.x >> 6, lane = threadIdx.x & 63;
    for (int e = blockIdx.x * 4 + wid; e < N_EDGES; e += gridDim.x * 4) {
        int t = etype[e];
        int s = eidx[e];
        int d = eidx[N_EDGES + e];
        int nt = ntype[s];
        float xs = nf[(long)s * 64 + lane];
        const float* wcol = &wn[nt * 4096 + lane];
        float xo = 0.f;
#pragma unroll 16
        for (int k = 0; k < 64; ++k) xo = fmaf(__shfl(xs, k), wcol[k * 64], xo);
        float ev = ef[(long)e * 32 + (lane & 31)];
        const float* mcol = &wm[t * 96 * 64 + lane];
        float m = 0.f;
#pragma unroll 16
        for (int k = 0; k < 64; ++k) m = fmaf(__shfl(xo, k), mcol[k * 64], m);
#pragma unroll 8
        for (int k = 0; k < 32; ++k) m = fmaf(__shfl(ev, k), mcol[(64 + k) * 64], m);
        atomicAdd(&out[(long)d * 64 + lane], m);
    }
}

// ---------------------------------------------------------------------------
extern "C" void kernel_launch(void* const* d_in, const int* in_sizes, int n_in,
                              void* d_out, int out_size, void* d_ws, size_t ws_size,
                              hipStream_t stream) {
    const float* nf    = (const float*)d_in[0];
    const float* ef    = (const float*)d_in[1];
    const float* Wn    = (const float*)d_in[2];
    const float* Wm    = (const float*)d_in[3];
    const int*   ntype = (const int*)d_in[4];
    const int*   etype = (const int*)d_in[5];
    const int*   eidx  = (const int*)d_in[6];
    float* out = (float*)d_out;

    const size_t xout_bytes = (size_t)N_NODES * 64 * 4;       // 25.6 MB
    const size_t b_bytes    = (size_t)N_NODES * KCAT * 4;     // 115.2 MB

    if (ws_size >= xout_bytes + b_bytes) {
        float* xout = (float*)d_ws;
        float* B    = (float*)((char*)d_ws + xout_bytes);
        zero_buf<<<2048, 256, 0, stream>>>((float4*)B, (long)(b_bytes / 16));
        node_xform<<<(N_NODES + 3) / 4, 256, 0, stream>>>(nf, Wn, ntype, xout);
        edge_scatter<<<2048, 256, 0, stream>>>(xout, ef, etype, eidx, B);
        final_gemm<<<(N_NODES + 63) / 64, 256, 0, stream>>>(B, Wm, out);
    } else {
        zero_buf<<<2048, 256, 0, stream>>>((float4*)d_out, (long)((size_t)out_size * 4 / 16));
        fallback_edge<<<4096, 256, 0, stream>>>(nf, ef, Wn, Wm, ntype, etype, eidx, out);
    }
}

// Round 2
// 574.424 us; speedup vs baseline: 1.2428x; 1.2428x over previous
//
#include <hip/hip_runtime.h>

#define N_NODES 100000
#define N_EDGES 1600000
#define D_IN 64
#define D_OUT 64
#define E_DIM 32
#define KCAT 288          // 3*64 (S buckets) + 3*32 (T buckets)
#define NBCHUNK 98        // ceil(100000 / 1024)

// ---------------------------------------------------------------------------
// zero helper (capture-safe, no hipMemsetAsync)
// ---------------------------------------------------------------------------
__global__ __launch_bounds__(256) void zero_buf(float4* __restrict__ p, long n4) {
    long i = (long)blockIdx.x * 256 + threadIdx.x;
    long stride = (long)gridDim.x * 256;
    float4 z = make_float4(0.f, 0.f, 0.f, 0.f);
    for (; i < n4; i += stride) p[i] = z;
}

// ---------------------------------------------------------------------------
// K1: x_out[n] = node_feature[n] @ W_node[node_type[n]]   (wave per node)
// ---------------------------------------------------------------------------
__global__ __launch_bounds__(256) void node_xform(const float* __restrict__ nf,
                                                  const float* __restrict__ Wn,
                                                  const int* __restrict__ ntype,
                                                  float* __restrict__ xout) {
    __shared__ float wl[2 * 64 * 64];   // 32 KB, both node-type matrices
    for (int i = threadIdx.x; i < 2 * 64 * 64; i += 256) wl[i] = Wn[i];
    __syncthreads();
    int wid = threadIdx.x >> 6, lane = threadIdx.x & 63;
    int n = blockIdx.x * 4 + wid;
    if (n >= N_NODES) return;
    int t = ntype[n];                       // wave-uniform
    float x = nf[n * 64 + lane];            // lane k holds row element k
    const float* wcol = &wl[t * 4096 + lane];  // column `lane`, stride 64
    float acc = 0.f;
#pragma unroll
    for (int k = 0; k < 64; ++k)
        acc = fmaf(__shfl(x, k), wcol[k * 64], acc);
    xout[n * 64 + lane] = acc;
}

// ---------------------------------------------------------------------------
// Counting sort by dst: count -> scan (3 kernels) -> placement
// ---------------------------------------------------------------------------
__global__ __launch_bounds__(256) void count_dst(const int* __restrict__ eidx,
                                                 int* __restrict__ cnt) {
    int i = blockIdx.x * 256 + threadIdx.x;
    int stride = gridDim.x * 256;
    for (; i < N_EDGES; i += stride) atomicAdd(&cnt[eidx[N_EDGES + i]], 1);
}

__global__ __launch_bounds__(256) void scan_a(const int* __restrict__ cnt,
                                              int* __restrict__ partials) {
    __shared__ int ws[4];
    int b = blockIdx.x, tid = threadIdx.x, lane = tid & 63, wid = tid >> 6;
    int i0 = b * 1024 + tid * 4;
    int s = 0;
#pragma unroll
    for (int k = 0; k < 4; ++k) { int i = i0 + k; if (i < N_NODES) s += cnt[i]; }
#pragma unroll
    for (int d = 32; d > 0; d >>= 1) s += __shfl_down(s, d);
    if (lane == 0) ws[wid] = s;
    __syncthreads();
    if (tid == 0) partials[b] = ws[0] + ws[1] + ws[2] + ws[3];
}

__global__ void scan_b(int* __restrict__ partials) {
    if (threadIdx.x == 0 && blockIdx.x == 0) {
        int run = 0;
        for (int i = 0; i < NBCHUNK; ++i) { int t = partials[i]; partials[i] = run; run += t; }
    }
}

__global__ __launch_bounds__(256) void scan_c(const int* __restrict__ cnt,
                                              const int* __restrict__ partials,
                                              int* __restrict__ offs,
                                              int* __restrict__ cursor) {
    __shared__ int wsum[4];
    int b = blockIdx.x, tid = threadIdx.x, lane = tid & 63, wid = tid >> 6;
    int i0 = b * 1024 + tid * 4;
    int c0 = (i0 + 0 < N_NODES) ? cnt[i0 + 0] : 0;
    int c1 = (i0 + 1 < N_NODES) ? cnt[i0 + 1] : 0;
    int c2 = (i0 + 2 < N_NODES) ? cnt[i0 + 2] : 0;
    int c3 = (i0 + 3 < N_NODES) ? cnt[i0 + 3] : 0;
    int lsum = c0 + c1 + c2 + c3;
    int v = lsum;
#pragma unroll
    for (int d = 1; d < 64; d <<= 1) {
        int u = __shfl_up(v, d);
        if (lane >= d) v += u;
    }
    int wexcl = v - lsum;                 // exclusive within wave
    if (lane == 63) wsum[wid] = v;        // wave total
    __syncthreads();
    int bexcl = 0;
    for (int w = 0; w < wid; ++w) bexcl += wsum[w];
    int base = partials[b] + bexcl + wexcl;
    if (i0 + 0 < N_NODES) { offs[i0 + 0] = base; cursor[i0 + 0] = base; } base += c0;
    if (i0 + 1 < N_NODES) { offs[i0 + 1] = base; cursor[i0 + 1] = base; } base += c1;
    if (i0 + 2 < N_NODES) { offs[i0 + 2] = base; cursor[i0 + 2] = base; } base += c2;
    if (i0 + 3 < N_NODES) { offs[i0 + 3] = base; cursor[i0 + 3] = base; }
}

__global__ __launch_bounds__(256) void place_edges(const int* __restrict__ eidx,
                                                   int* __restrict__ cursor,
                                                   int* __restrict__ perm) {
    int i = blockIdx.x * 256 + threadIdx.x;
    int stride = gridDim.x * 256;
    for (; i < N_EDGES; i += stride) {
        int d = eidx[N_EDGES + i];
        int pos = atomicAdd(&cursor[d], 1);
        perm[pos] = i;
    }
}

// ---------------------------------------------------------------------------
// Pull-side aggregate: wave per node, zero atomics.
//   B[n][t*64 + c]        = sum over in-edges of type t of x_out[src][c]
//   B[n][192 + t*32 + c]  = sum over in-edges of type t of ef[e][c]
// ---------------------------------------------------------------------------
__global__ __launch_bounds__(256) void aggregate(const int* __restrict__ perm,
                                                 const int* __restrict__ offs,
                                                 const int* __restrict__ cnt,
                                                 const int* __restrict__ etype,
                                                 const int* __restrict__ eidx,
                                                 const float* __restrict__ xout,
                                                 const float* __restrict__ ef,
                                                 float* __restrict__ B) {
    int wid = threadIdx.x >> 6, lane = threadIdx.x & 63;
    int n = blockIdx.x * 4 + wid;
    if (n >= N_NODES) return;
    int start = offs[n], c = cnt[n];
    float a0 = 0.f, a1 = 0.f, a2 = 0.f, b0 = 0.f, b1 = 0.f, b2 = 0.f;
    int i = 0;
    for (; i + 4 <= c; i += 4) {
        int e0 = perm[start + i + 0];
        int e1 = perm[start + i + 1];
        int e2 = perm[start + i + 2];
        int e3 = perm[start + i + 3];
        int t0 = etype[e0], t1 = etype[e1], t2 = etype[e2], t3 = etype[e3];
        int s0 = eidx[e0], s1 = eidx[e1], s2 = eidx[e2], s3 = eidx[e3];
        float x0 = xout[(size_t)s0 * 64 + lane];
        float x1 = xout[(size_t)s1 * 64 + lane];
        float x2 = xout[(size_t)s2 * 64 + lane];
        float x3 = xout[(size_t)s3 * 64 + lane];
        float v0 = 0.f, v1 = 0.f, v2 = 0.f, v3 = 0.f;
        if (lane < 32) {
            v0 = ef[(size_t)e0 * 32 + lane];
            v1 = ef[(size_t)e1 * 32 + lane];
            v2 = ef[(size_t)e2 * 32 + lane];
            v3 = ef[(size_t)e3 * 32 + lane];
        }
        if (t0 == 0) { a0 += x0; b0 += v0; } else if (t0 == 1) { a1 += x0; b1 += v0; } else { a2 += x0; b2 += v0; }
        if (t1 == 0) { a0 += x1; b0 += v1; } else if (t1 == 1) { a1 += x1; b1 += v1; } else { a2 += x1; b2 += v1; }
        if (t2 == 0) { a0 += x2; b0 += v2; } else if (t2 == 1) { a1 += x2; b1 += v2; } else { a2 += x2; b2 += v2; }
        if (t3 == 0) { a0 += x3; b0 += v3; } else if (t3 == 1) { a1 += x3; b1 += v3; } else { a2 += x3; b2 += v3; }
    }
    for (; i < c; ++i) {
        int e = perm[start + i];
        int t = etype[e];
        int s = eidx[e];
        float xv = xout[(size_t)s * 64 + lane];
        float ev = (lane < 32) ? ef[(size_t)e * 32 + lane] : 0.f;
        if (t == 0) { a0 += xv; b0 += ev; } else if (t == 1) { a1 += xv; b1 += ev; } else { a2 += xv; b2 += ev; }
    }
    float* Bn = &B[(size_t)n * KCAT];
    Bn[lane] = a0; Bn[64 + lane] = a1; Bn[128 + lane] = a2;
    if (lane < 32) { Bn[192 + lane] = b0; Bn[224 + lane] = b1; Bn[256 + lane] = b2; }
}

// ---------------------------------------------------------------------------
// K3: out = B @ Wcat, Wcat[288][64] assembled on the fly from W_msg.
// ---------------------------------------------------------------------------
__global__ __launch_bounds__(256) void final_gemm(const float* __restrict__ B,
                                                  const float* __restrict__ Wm,
                                                  float* __restrict__ out) {
    __shared__ float As[64][33];   // +1 pad
    __shared__ float Ws[32][64];
    int tid = threadIdx.x;
    int n0 = blockIdx.x * 64;
    int tx = tid & 15;    // output col quad
    int ty = tid >> 4;    // node quad
    float acc[4][4] = {};

    for (int k0 = 0; k0 < KCAT; k0 += 32) {
#pragma unroll
        for (int i = 0; i < 8; ++i) {
            int f = i * 256 + tid;
            int r = f >> 5, cc = f & 31;
            int n = n0 + r;
            As[r][cc] = (n < N_NODES) ? B[(long)n * KCAT + k0 + cc] : 0.f;
        }
#pragma unroll
        for (int i = 0; i < 8; ++i) {
            int f = i * 256 + tid;
            int kk = f >> 6, j = f & 63;
            int r = k0 + kk;
            int t, kin;
            if (r < 192) { t = r >> 6; kin = r & 63; }
            else         { int q = r - 192; t = q >> 5; kin = 64 + (q & 31); }
            Ws[kk][j] = Wm[(t * 96 + kin) * 64 + j];
        }
        __syncthreads();
#pragma unroll
        for (int kk = 0; kk < 32; ++kk) {
            float a0 = As[ty * 4 + 0][kk];
            float a1 = As[ty * 4 + 1][kk];
            float a2 = As[ty * 4 + 2][kk];
            float a3 = As[ty * 4 + 3][kk];
            float4 w = *(const float4*)&Ws[kk][tx * 4];
            acc[0][0] = fmaf(a0, w.x, acc[0][0]); acc[0][1] = fmaf(a0, w.y, acc[0][1]);
            acc[0][2] = fmaf(a0, w.z, acc[0][2]); acc[0][3] = fmaf(a0, w.w, acc[0][3]);
            acc[1][0] = fmaf(a1, w.x, acc[1][0]); acc[1][1] = fmaf(a1, w.y, acc[1][1]);
            acc[1][2] = fmaf(a1, w.z, acc[1][2]); acc[1][3] = fmaf(a1, w.w, acc[1][3]);
            acc[2][0] = fmaf(a2, w.x, acc[2][0]); acc[2][1] = fmaf(a2, w.y, acc[2][1]);
            acc[2][2] = fmaf(a2, w.z, acc[2][2]); acc[2][3] = fmaf(a2, w.w, acc[2][3]);
            acc[3][0] = fmaf(a3, w.x, acc[3][0]); acc[3][1] = fmaf(a3, w.y, acc[3][1]);
            acc[3][2] = fmaf(a3, w.z, acc[3][2]); acc[3][3] = fmaf(a3, w.w, acc[3][3]);
        }
        __syncthreads();
    }
#pragma unroll
    for (int r = 0; r < 4; ++r) {
        int n = n0 + ty * 4 + r;
        if (n < N_NODES) {
            float4 v = make_float4(acc[r][0], acc[r][1], acc[r][2], acc[r][3]);
            *(float4*)&out[(long)n * 64 + tx * 4] = v;
        }
    }
}

// ---------------------------------------------------------------------------
// Fallback (ws too small): direct wave-per-edge.
// ---------------------------------------------------------------------------
__global__ __launch_bounds__(256) void fallback_edge(const float* __restrict__ nf,
                                                     const float* __restrict__ ef,
                                                     const float* __restrict__ Wn,
                                                     const float* __restrict__ Wm,
                                                     const int* __restrict__ ntype,
                                                     const int* __restrict__ etype,
                                                     const int* __restrict__ eidx,
                                                     float* __restrict__ out) {
    __shared__ float wn[2 * 64 * 64];
    __shared__ float wm[3 * 96 * 64];
    for (int i = threadIdx.x; i < 2 * 64 * 64; i += 256) wn[i] = Wn[i];
    for (int i = threadIdx.x; i < 3 * 96 * 64; i += 256) wm[i] = Wm[i];
    __syncthreads();
    int wid = threadIdx.x >> 6, lane = threadIdx.x & 63;
    for (int e = blockIdx.x * 4 + wid; e < N_EDGES; e += gridDim.x * 4) {
        int t = etype[e];
        int s = eidx[e];
        int d = eidx[N_EDGES + e];
        int nt = ntype[s];
        float xs = nf[(long)s * 64 + lane];
        const float* wcol = &wn[nt * 4096 + lane];
        float xo = 0.f;
#pragma unroll 16
        for (int k = 0; k < 64; ++k) xo = fmaf(__shfl(xs, k), wcol[k * 64], xo);
        float ev = ef[(long)e * 32 + (lane & 31)];
        const float* mcol = &wm[t * 96 * 64 + lane];
        float m = 0.f;
#pragma unroll 16
        for (int k = 0; k < 64; ++k) m = fmaf(__shfl(xo, k), mcol[k * 64], m);
#pragma unroll 8
        for (int k = 0; k < 32; ++k) m = fmaf(__shfl(ev, k), mcol[(64 + k) * 64], m);
        atomicAdd(&out[(long)d * 64 + lane], m);
    }
}

// ---------------------------------------------------------------------------
extern "C" void kernel_launch(void* const* d_in, const int* in_sizes, int n_in,
                              void* d_out, int out_size, void* d_ws, size_t ws_size,
                              hipStream_t stream) {
    const float* nf    = (const float*)d_in[0];
    const float* ef    = (const float*)d_in[1];
    const float* Wn    = (const float*)d_in[2];
    const float* Wm    = (const float*)d_in[3];
    const int*   ntype = (const int*)d_in[4];
    const int*   etype = (const int*)d_in[5];
    const int*   eidx  = (const int*)d_in[6];
    float* out = (float*)d_out;

    const size_t xout_bytes = (size_t)N_NODES * 64 * 4;       // 25.6 MB
    const size_t b_bytes    = (size_t)N_NODES * KCAT * 4;     // 115.2 MB

    if (ws_size >= xout_bytes + b_bytes) {
        float* xout = (float*)d_ws;
        float* B    = (float*)((char*)d_ws + xout_bytes);
        // CSR scratch lives in d_out (7.6 MB < 25.6 MB); final_gemm overwrites
        // the whole of d_out at the end of the call.
        int* perm     = (int*)d_out;            // 1.6M ints
        int* cnt      = perm + N_EDGES;         // 100k
        int* offs     = cnt + N_NODES;          // 100k
        int* cursor   = offs + N_NODES;         // 100k
        int* partials = cursor + N_NODES;       // 98

        zero_buf<<<100, 256, 0, stream>>>((float4*)cnt, (long)(N_NODES / 4));
        node_xform<<<(N_NODES + 3) / 4, 256, 0, stream>>>(nf, Wn, ntype, xout);
        count_dst<<<2048, 256, 0, stream>>>(eidx, cnt);
        scan_a<<<NBCHUNK, 256, 0, stream>>>(cnt, partials);
        scan_b<<<1, 64, 0, stream>>>(partials);
        scan_c<<<NBCHUNK, 256, 0, stream>>>(cnt, partials, offs, cursor);
        place_edges<<<2048, 256, 0, stream>>>(eidx, cursor, perm);
        aggregate<<<(N_NODES + 3) / 4, 256, 0, stream>>>(perm, offs, cnt, etype, eidx, xout, ef, B);
        final_gemm<<<(N_NODES + 63) / 64, 256, 0, stream>>>(B, Wm, out);
    } else {
        zero_buf<<<2048, 256, 0, stream>>>((float4*)d_out, (long)((size_t)out_size * 4 / 16));
        fallback_edge<<<4096, 256, 0, stream>>>(nf, ef, Wn, Wm, ntype, etype, eidx, out);
    }
}

// Round 3
// 478.123 us; speedup vs baseline: 1.4931x; 1.2014x over previous
//
#include <hip/hip_runtime.h>
#include <hip/hip_bf16.h>

#define N_NODES 100000
#define N_EDGES 1600000
#define D_IN 64
#define D_OUT 64
#define E_DIM 32
#define KCAT 288          // 3*64 (S buckets) + 3*32 (T buckets)
#define NBCHUNK 98        // ceil(100000 / 1024)

typedef unsigned long long u64;
typedef __hip_bfloat16 bf16;

// ---------------------------------------------------------------------------
// zero helper (capture-safe)
// ---------------------------------------------------------------------------
__global__ __launch_bounds__(256) void zero_buf(float4* __restrict__ p, long n4) {
    long i = (long)blockIdx.x * 256 + threadIdx.x;
    long stride = (long)gridDim.x * 256;
    float4 z = make_float4(0.f, 0.f, 0.f, 0.f);
    for (; i < n4; i += stride) p[i] = z;
}

// ---------------------------------------------------------------------------
// K1: xout[n] = nf[n] @ W_node[ntype[n]]  (wave/node, grid-strided, bf16 out)
// ---------------------------------------------------------------------------
__global__ __launch_bounds__(256) void node_xform(const float* __restrict__ nf,
                                                  const float* __restrict__ Wn,
                                                  const int* __restrict__ ntype,
                                                  bf16* __restrict__ xout) {
    __shared__ float wl[2 * 64 * 64];   // 32 KB
    for (int i = threadIdx.x; i < 2 * 64 * 64; i += 256) wl[i] = Wn[i];
    __syncthreads();
    int wid = threadIdx.x >> 6, lane = threadIdx.x & 63;
    int gw = blockIdx.x * 4 + wid, nw = gridDim.x * 4;
    for (int n = gw; n < N_NODES; n += nw) {
        int t = ntype[n];                          // wave-uniform
        float x = nf[(size_t)n * 64 + lane];
        const float* wcol = &wl[t * 4096 + lane];
        float acc = 0.f;
#pragma unroll
        for (int k = 0; k < 64; ++k)
            acc = fmaf(__shfl(x, k), wcol[k * 64], acc);
        xout[(size_t)n * 64 + lane] = __float2bfloat16(acc);
    }
}

// ---------------------------------------------------------------------------
// Counting sort by dst
// ---------------------------------------------------------------------------
__global__ __launch_bounds__(256) void count_dst(const int* __restrict__ eidx,
                                                 int* __restrict__ cnt) {
    const int4* d4 = (const int4*)(eidx + N_EDGES);
    int i = blockIdx.x * 256 + threadIdx.x;
    int stride = gridDim.x * 256;
    for (; i < N_EDGES / 4; i += stride) {
        int4 v = d4[i];
        atomicAdd(&cnt[v.x], 1); atomicAdd(&cnt[v.y], 1);
        atomicAdd(&cnt[v.z], 1); atomicAdd(&cnt[v.w], 1);
    }
}

__global__ __launch_bounds__(256) void scan_a(const int* __restrict__ cnt,
                                              int* __restrict__ partials) {
    __shared__ int ws[4];
    int b = blockIdx.x, tid = threadIdx.x, lane = tid & 63, wid = tid >> 6;
    int i0 = b * 1024 + tid * 4;
    int s = 0;
#pragma unroll
    for (int k = 0; k < 4; ++k) { int i = i0 + k; if (i < N_NODES) s += cnt[i]; }
#pragma unroll
    for (int d = 32; d > 0; d >>= 1) s += __shfl_down(s, d);
    if (lane == 0) ws[wid] = s;
    __syncthreads();
    if (tid == 0) partials[b] = ws[0] + ws[1] + ws[2] + ws[3];
}

// single-block LDS scan (replaces serial 1-thread loop)
__global__ __launch_bounds__(128) void scan_b(int* __restrict__ partials) {
    __shared__ int s[128];
    int tid = threadIdx.x;
    int v = (tid < NBCHUNK) ? partials[tid] : 0;
    s[tid] = v;
    __syncthreads();
    for (int d = 1; d < 128; d <<= 1) {
        int u = (tid >= d) ? s[tid - d] : 0;
        __syncthreads();
        s[tid] += u;
        __syncthreads();
    }
    if (tid < NBCHUNK) partials[tid] = s[tid] - v;   // exclusive
}

__global__ __launch_bounds__(256) void scan_c(const int* __restrict__ cnt,
                                              const int* __restrict__ partials,
                                              int* __restrict__ offs,
                                              int* __restrict__ cursor) {
    __shared__ int wsum[4];
    int b = blockIdx.x, tid = threadIdx.x, lane = tid & 63, wid = tid >> 6;
    int i0 = b * 1024 + tid * 4;
    int c0 = (i0 + 0 < N_NODES) ? cnt[i0 + 0] : 0;
    int c1 = (i0 + 1 < N_NODES) ? cnt[i0 + 1] : 0;
    int c2 = (i0 + 2 < N_NODES) ? cnt[i0 + 2] : 0;
    int c3 = (i0 + 3 < N_NODES) ? cnt[i0 + 3] : 0;
    int lsum = c0 + c1 + c2 + c3;
    int v = lsum;
#pragma unroll
    for (int d = 1; d < 64; d <<= 1) {
        int u = __shfl_up(v, d);
        if (lane >= d) v += u;
    }
    int wexcl = v - lsum;
    if (lane == 63) wsum[wid] = v;
    __syncthreads();
    int bexcl = 0;
    for (int w = 0; w < wid; ++w) bexcl += wsum[w];
    int base = partials[b] + bexcl + wexcl;
    if (i0 + 0 < N_NODES) { offs[i0 + 0] = base; cursor[i0 + 0] = base; } base += c0;
    if (i0 + 1 < N_NODES) { offs[i0 + 1] = base; cursor[i0 + 1] = base; } base += c1;
    if (i0 + 2 < N_NODES) { offs[i0 + 2] = base; cursor[i0 + 2] = base; } base += c2;
    if (i0 + 3 < N_NODES) { offs[i0 + 3] = base; cursor[i0 + 3] = base; }
}

// payload: bits[0:17)=src, [17:19)=etype, [19:..)=edge id
__global__ __launch_bounds__(256) void place_edges(const int* __restrict__ eidx,
                                                   const int* __restrict__ etype,
                                                   int* __restrict__ cursor,
                                                   u64* __restrict__ pay) {
    const int4* d4 = (const int4*)(eidx + N_EDGES);
    const int4* s4 = (const int4*)eidx;
    const int4* t4 = (const int4*)etype;
    int i = blockIdx.x * 256 + threadIdx.x;
    int stride = gridDim.x * 256;
    for (; i < N_EDGES / 4; i += stride) {
        int4 d = d4[i]; int4 s = s4[i]; int4 t = t4[i];
        int e0 = i * 4;
        int p;
        p = atomicAdd(&cursor[d.x], 1); pay[p] = (u64)s.x | ((u64)t.x << 17) | ((u64)(e0 + 0) << 19);
        p = atomicAdd(&cursor[d.y], 1); pay[p] = (u64)s.y | ((u64)t.y << 17) | ((u64)(e0 + 1) << 19);
        p = atomicAdd(&cursor[d.z], 1); pay[p] = (u64)s.z | ((u64)t.z << 17) | ((u64)(e0 + 2) << 19);
        p = atomicAdd(&cursor[d.w], 1); pay[p] = (u64)s.w | ((u64)t.w << 17) | ((u64)(e0 + 3) << 19);
    }
}

// ---------------------------------------------------------------------------
// Pull-side aggregate: wave/node, zero atomics, single sequential payload
// stream (batch-64 coalesced load + shfl broadcast), bf16 B output.
// ---------------------------------------------------------------------------
__global__ __launch_bounds__(256) void aggregate(const u64* __restrict__ pay,
                                                 const int* __restrict__ offs,
                                                 const int* __restrict__ cnt,
                                                 const bf16* __restrict__ xout,
                                                 const float* __restrict__ ef,
                                                 bf16* __restrict__ B) {
    int wid = threadIdx.x >> 6, lane = threadIdx.x & 63;
    int n = blockIdx.x * 4 + wid;
    if (n >= N_NODES) return;
    int start = offs[n], c = cnt[n];
    float a0 = 0.f, a1 = 0.f, a2 = 0.f, b0 = 0.f, b1 = 0.f, b2 = 0.f;

    for (int base = 0; base < c; base += 64) {
        int m = c - base; if (m > 64) m = 64;
        u64 p = 0;
        if (lane < m) p = pay[start + base + lane];
        int j = 0;
        for (; j + 4 <= m; j += 4) {
            u64 p0 = __shfl(p, j + 0), p1 = __shfl(p, j + 1);
            u64 p2 = __shfl(p, j + 2), p3 = __shfl(p, j + 3);
            int s0 = (int)(p0 & 0x1FFFF), t0 = (int)((p0 >> 17) & 3); long e0 = (long)(p0 >> 19);
            int s1 = (int)(p1 & 0x1FFFF), t1 = (int)((p1 >> 17) & 3); long e1 = (long)(p1 >> 19);
            int s2 = (int)(p2 & 0x1FFFF), t2 = (int)((p2 >> 17) & 3); long e2 = (long)(p2 >> 19);
            int s3 = (int)(p3 & 0x1FFFF), t3 = (int)((p3 >> 17) & 3); long e3 = (long)(p3 >> 19);
            float x0 = __bfloat162float(xout[(size_t)s0 * 64 + lane]);
            float x1 = __bfloat162float(xout[(size_t)s1 * 64 + lane]);
            float x2 = __bfloat162float(xout[(size_t)s2 * 64 + lane]);
            float x3 = __bfloat162float(xout[(size_t)s3 * 64 + lane]);
            float v0 = 0.f, v1 = 0.f, v2 = 0.f, v3 = 0.f;
            if (lane < 32) {
                v0 = ef[e0 * 32 + lane]; v1 = ef[e1 * 32 + lane];
                v2 = ef[e2 * 32 + lane]; v3 = ef[e3 * 32 + lane];
            }
            // t* are wave-uniform -> scalar branches, no divergence
            if (t0 == 0) { a0 += x0; b0 += v0; } else if (t0 == 1) { a1 += x0; b1 += v0; } else { a2 += x0; b2 += v0; }
            if (t1 == 0) { a0 += x1; b0 += v1; } else if (t1 == 1) { a1 += x1; b1 += v1; } else { a2 += x1; b2 += v1; }
            if (t2 == 0) { a0 += x2; b0 += v2; } else if (t2 == 1) { a1 += x2; b1 += v2; } else { a2 += x2; b2 += v2; }
            if (t3 == 0) { a0 += x3; b0 += v3; } else if (t3 == 1) { a1 += x3; b1 += v3; } else { a2 += x3; b2 += v3; }
        }
        for (; j < m; ++j) {
            u64 pj = __shfl(p, j);
            int s = (int)(pj & 0x1FFFF), t = (int)((pj >> 17) & 3); long e = (long)(pj >> 19);
            float xv = __bfloat162float(xout[(size_t)s * 64 + lane]);
            float ev = (lane < 32) ? ef[e * 32 + lane] : 0.f;
            if (t == 0) { a0 += xv; b0 += ev; } else if (t == 1) { a1 += xv; b1 += ev; } else { a2 += xv; b2 += ev; }
        }
    }
    bf16* Bn = B + (size_t)n * KCAT;
    Bn[lane]       = __float2bfloat16(a0);
    Bn[64 + lane]  = __float2bfloat16(a1);
    Bn[128 + lane] = __float2bfloat16(a2);
    if (lane < 32) {
        Bn[192 + lane] = __float2bfloat16(b0);
        Bn[224 + lane] = __float2bfloat16(b1);
        Bn[256 + lane] = __float2bfloat16(b2);
    }
}

// ---------------------------------------------------------------------------
// K3: out = B(bf16) @ Wcat(fp32), Wcat[288][64] remapped from W_msg on load.
// ---------------------------------------------------------------------------
__global__ __launch_bounds__(256) void final_gemm(const bf16* __restrict__ B,
                                                  const float* __restrict__ Wm,
                                                  float* __restrict__ out) {
    __shared__ float As[64][33];   // +1 pad
    __shared__ float Ws[32][64];
    int tid = threadIdx.x;
    int n0 = blockIdx.x * 64;
    int tx = tid & 15;
    int ty = tid >> 4;
    float acc[4][4] = {};

    for (int k0 = 0; k0 < KCAT; k0 += 32) {
#pragma unroll
        for (int i = 0; i < 8; ++i) {
            int f = i * 256 + tid;
            int r = f >> 5, cc = f & 31;
            int n = n0 + r;
            As[r][cc] = (n < N_NODES) ? __bfloat162float(B[(size_t)n * KCAT + k0 + cc]) : 0.f;
        }
#pragma unroll
        for (int i = 0; i < 8; ++i) {
            int f = i * 256 + tid;
            int kk = f >> 6, j = f & 63;
            int r = k0 + kk;
            int t, kin;
            if (r < 192) { t = r >> 6; kin = r & 63; }
            else         { int q = r - 192; t = q >> 5; kin = 64 + (q & 31); }
            Ws[kk][j] = Wm[(t * 96 + kin) * 64 + j];
        }
        __syncthreads();
#pragma unroll
        for (int kk = 0; kk < 32; ++kk) {
            float a0 = As[ty * 4 + 0][kk];
            float a1 = As[ty * 4 + 1][kk];
            float a2 = As[ty * 4 + 2][kk];
            float a3 = As[ty * 4 + 3][kk];
            float4 w = *(const float4*)&Ws[kk][tx * 4];
            acc[0][0] = fmaf(a0, w.x, acc[0][0]); acc[0][1] = fmaf(a0, w.y, acc[0][1]);
            acc[0][2] = fmaf(a0, w.z, acc[0][2]); acc[0][3] = fmaf(a0, w.w, acc[0][3]);
            acc[1][0] = fmaf(a1, w.x, acc[1][0]); acc[1][1] = fmaf(a1, w.y, acc[1][1]);
            acc[1][2] = fmaf(a1, w.z, acc[1][2]); acc[1][3] = fmaf(a1, w.w, acc[1][3]);
            acc[2][0] = fmaf(a2, w.x, acc[2][0]); acc[2][1] = fmaf(a2, w.y, acc[2][1]);
            acc[2][2] = fmaf(a2, w.z, acc[2][2]); acc[2][3] = fmaf(a2, w.w, acc[2][3]);
            acc[3][0] = fmaf(a3, w.x, acc[3][0]); acc[3][1] = fmaf(a3, w.y, acc[3][1]);
            acc[3][2] = fmaf(a3, w.z, acc[3][2]); acc[3][3] = fmaf(a3, w.w, acc[3][3]);
        }
        __syncthreads();
    }
#pragma unroll
    for (int r = 0; r < 4; ++r) {
        int n = n0 + ty * 4 + r;
        if (n < N_NODES) {
            float4 v = make_float4(acc[r][0], acc[r][1], acc[r][2], acc[r][3]);
            *(float4*)&out[(size_t)n * 64 + tx * 4] = v;
        }
    }
}

// ---------------------------------------------------------------------------
// Fallback (ws too small): direct wave-per-edge, fp32.
// ---------------------------------------------------------------------------
__global__ __launch_bounds__(256) void fallback_edge(const float* __restrict__ nf,
                                                     const float* __restrict__ ef,
                                                     const float* __restrict__ Wn,
                                                     const float* __restrict__ Wm,
                                                     const int* __restrict__ ntype,
                                                     const int* __restrict__ etype,
                                                     const int* __restrict__ eidx,
                                                     float* __restrict__ out) {
    __shared__ float wn[2 * 64 * 64];
    __shared__ float wm[3 * 96 * 64];
    for (int i = threadIdx.x; i < 2 * 64 * 64; i += 256) wn[i] = Wn[i];
    for (int i = threadIdx.x; i < 3 * 96 * 64; i += 256) wm[i] = Wm[i];
    __syncthreads();
    int wid = threadIdx.x >> 6, lane = threadIdx.x & 63;
    for (int e = blockIdx.x * 4 + wid; e < N_EDGES; e += gridDim.x * 4) {
        int t = etype[e];
        int s = eidx[e];
        int d = eidx[N_EDGES + e];
        int nt = ntype[s];
        float xs = nf[(long)s * 64 + lane];
        const float* wcol = &wn[nt * 4096 + lane];
        float xo = 0.f;
#pragma unroll 16
        for (int k = 0; k < 64; ++k) xo = fmaf(__shfl(xs, k), wcol[k * 64], xo);
        float ev = ef[(long)e * 32 + (lane & 31)];
        const float* mcol = &wm[t * 96 * 64 + lane];
        float m = 0.f;
#pragma unroll 16
        for (int k = 0; k < 64; ++k) m = fmaf(__shfl(xo, k), mcol[k * 64], m);
#pragma unroll 8
        for (int k = 0; k < 32; ++k) m = fmaf(__shfl(ev, k), mcol[(64 + k) * 64], m);
        atomicAdd(&out[(long)d * 64 + lane], m);
    }
}

// ---------------------------------------------------------------------------
extern "C" void kernel_launch(void* const* d_in, const int* in_sizes, int n_in,
                              void* d_out, int out_size, void* d_ws, size_t ws_size,
                              hipStream_t stream) {
    const float* nf    = (const float*)d_in[0];
    const float* ef    = (const float*)d_in[1];
    const float* Wn    = (const float*)d_in[2];
    const float* Wm    = (const float*)d_in[3];
    const int*   ntype = (const int*)d_in[4];
    const int*   etype = (const int*)d_in[5];
    const int*   eidx  = (const int*)d_in[6];
    float* out = (float*)d_out;

    const size_t xout_bytes = (size_t)N_NODES * 64 * 2;        // 12.8 MB bf16
    const size_t b_bytes    = (size_t)N_NODES * KCAT * 2;      // 57.6 MB bf16
    const size_t meta_bytes = (size_t)(3 * N_NODES + 256) * 4; // cnt/offs/cursor/partials

    if (ws_size >= xout_bytes + b_bytes + meta_bytes) {
        bf16* xout = (bf16*)d_ws;
        bf16* B    = (bf16*)((char*)d_ws + xout_bytes);
        int* cnt      = (int*)((char*)d_ws + xout_bytes + b_bytes);
        int* offs     = cnt + N_NODES;
        int* cursor   = offs + N_NODES;
        int* partials = cursor + N_NODES;
        // payload lives in d_out (12.8 MB < 25.6 MB); final_gemm fully
        // overwrites d_out at the end of every call.
        u64* pay = (u64*)d_out;

        zero_buf<<<100, 256, 0, stream>>>((float4*)cnt, (long)(N_NODES / 4));
        node_xform<<<1563, 256, 0, stream>>>(nf, Wn, ntype, xout);
        count_dst<<<1024, 256, 0, stream>>>(eidx, cnt);
        scan_a<<<NBCHUNK, 256, 0, stream>>>(cnt, partials);
        scan_b<<<1, 128, 0, stream>>>(partials);
        scan_c<<<NBCHUNK, 256, 0, stream>>>(cnt, partials, offs, cursor);
        place_edges<<<1024, 256, 0, stream>>>(eidx, etype, cursor, pay);
        aggregate<<<(N_NODES + 3) / 4, 256, 0, stream>>>(pay, offs, cnt, xout, ef, B);
        final_gemm<<<(N_NODES + 63) / 64, 256, 0, stream>>>(B, Wm, out);
    } else {
        zero_buf<<<2048, 256, 0, stream>>>((float4*)d_out, (long)((size_t)out_size * 4 / 16));
        fallback_edge<<<4096, 256, 0, stream>>>(nf, ef, Wn, Wm, ntype, etype, eidx, out);
    }
}